// Round 15
// baseline (2643.875 us; speedup 1.0000x reference)
//
#include <hip/hip_runtime.h>
#include <stdint.h>

typedef unsigned short u16;

#define T_STEPS 512
#define BATCH   64
#define DIN     512
#define HID     1024
#define G4      4096
#define NBLK    128
#define NH      8       // hidden units per block
#define NC      32      // gate columns per block; col c = u*4 + gate
#define THREADS 512

#define U_LD    1032    // 1024 + 8 pad (init staging only)
#define W_LD    520     // 512 + 8 pad  (init staging only)

// LDS: init  Ut[NC*U_LD] @0 (66048B), Wt[NC*W_LD] @66048 (33280B)
//      run   zp f32[8][32][36] @0 (36864B)
#define SM_BYTES 99328
#define WT_OFF   66048

// ws map
#define XB_BYTES ((size_t)T_STEPS * BATCH * DIN * 2)   // 32 MB bf16 x
#define HB_OFF   XB_BYTES            // h: [ch2][par2][kblk128][row32][8u] bf16
#define HB_BYTES (2u * 2u * 128 * 32 * 8 * 2)          // 256 KB
#define FLG_OFF  (HB_OFF + HB_BYTES) // flags [ch2][blk128][gw4] x 16B = 16 KB
#define FLG_BYTES (2 * 128 * 4 * 16)
#define WS_NEED  (FLG_OFF + FLG_BYTES)

typedef float f32x16 __attribute__((ext_vector_type(16)));
typedef short bf16x8 __attribute__((ext_vector_type(8)));
typedef unsigned uint32x4 __attribute__((ext_vector_type(4)));

__device__ __forceinline__ u16 f2bf(float f) {
  unsigned u = __float_as_uint(f);
  u += 0x7fffu + ((u >> 16) & 1u);   // RNE
  return (u16)(u >> 16);
}
__device__ __forceinline__ float sigm(float x) {
  return __builtin_amdgcn_rcpf(1.f + __expf(-x));
}
__device__ __forceinline__ float fast_tanh(float x) {
  return 1.f - 2.f * __builtin_amdgcn_rcpf(__expf(2.f * x) + 1.f);
}

// sc0 sc1 = coherence-point access (bypass L1/L2); flat 64b VGPR address.
__device__ __forceinline__ uint32x4 load16_sc(uint64_t addr) {
  uint32x4 d;
  asm volatile("global_load_dwordx4 %0, %1, off sc0 sc1" : "=v"(d) : "v"(addr));
  return d;
}
__device__ __forceinline__ uint32x4 load16_plain(uint64_t addr) {
  uint32x4 d;
  asm volatile("global_load_dwordx4 %0, %1, off" : "=v"(d) : "v"(addr));
  return d;
}
__device__ __forceinline__ unsigned load4_sc(uint64_t addr) {
  unsigned d;
  asm volatile("global_load_dword %0, %1, off sc0 sc1" : "=v"(d) : "v"(addr));
  return d;
}
__device__ __forceinline__ void store16_sc(uint64_t addr, uint32x4 v) {
  asm volatile("global_store_dwordx4 %0, %1, off sc0 sc1" :: "v"(addr), "v"(v) : "memory");
}
__device__ __forceinline__ void store4_sc(uint64_t addr, unsigned v) {
  asm volatile("global_store_dword %0, %1, off sc0 sc1" :: "v"(addr), "v"(v) : "memory");
}
#define WAITV(n) asm volatile("s_waitcnt vmcnt(" #n ")" ::: "memory")
#define SBAR()   __builtin_amdgcn_sched_barrier(0)

// x[B][T][D] fp32 -> xb[T][B][D] bf16
__global__ void cvt_x(const float* __restrict__ x, u16* __restrict__ xb) {
  int i = blockIdx.x * 256 + threadIdx.x;
  int dblk = i & 63;
  int rest = i >> 6;
  int b = rest & 63;
  int t = rest >> 6;
  const float4* s = reinterpret_cast<const float4*>(x + ((size_t)(b * T_STEPS + t)) * DIN + dblk * 8);
  float4 f0 = s[0], f1 = s[1];
  uint4 o;
  o.x = (unsigned)f2bf(f0.x) | ((unsigned)f2bf(f0.y) << 16);
  o.y = (unsigned)f2bf(f0.z) | ((unsigned)f2bf(f0.w) << 16);
  o.z = (unsigned)f2bf(f1.x) | ((unsigned)f2bf(f1.y) << 16);
  o.w = (unsigned)f2bf(f1.z) | ((unsigned)f2bf(f1.w) << 16);
  *reinterpret_cast<uint4*>(xb + ((size_t)(t * BATCH + b)) * DIN + dblk * 8) = o;
}

// Dual-chain persistent LSTM. Chains = batch halves (rows 0-31 / 32-63),
// alternating phases; chain Y's phase hides chain X's publish->poll->load RTs.
// Per phase: 8 waves = 8 exclusive K-splits (128 HID + 64 DIN each), M=32,
// N=32 gate-interleaved cols; 12 MFMAs/wave; zp 8-way reduce; gate waves
// publish+ack+flag IMMEDIATELY (no cross-chain coupling), then poll+prefetch;
// non-gate waves poll+prefetch right after the zp barrier.
__launch_bounds__(THREADS)
__global__ void lstm_kernel(const float* __restrict__ W, const float* __restrict__ U,
                            const float* __restrict__ bias, const u16* __restrict__ xb,
                            char* __restrict__ ws, float* __restrict__ out) {
  __shared__ __align__(16) char smraw[SM_BYTES];
  u16* Ut = (u16*)smraw;
  u16* Wt = (u16*)(smraw + WT_OFF);
  float (*zp)[32][36] = (float(*)[32][36])smraw;   // run phase

  const int tid = threadIdx.x;
  const int bid = blockIdx.x;
  const int j0 = bid * NH;

  // ---- init: stage transposed bf16 weight slices (col c = u*4 + gate) ----
  for (int idx = tid; idx < NC * HID; idx += THREADS) {
    int c = idx & (NC - 1);
    int k = idx >> 5;
    int gcol = ((c & 3) << 10) + j0 + (c >> 2);
    Ut[c * U_LD + k] = f2bf(U[(size_t)k * G4 + gcol]);
  }
  for (int idx = tid; idx < NC * DIN; idx += THREADS) {
    int c = idx & (NC - 1);
    int k = idx >> 5;
    int gcol = ((c & 3) << 10) + j0 + (c >> 2);
    Wt[c * W_LD + k] = f2bf(W[(size_t)k * G4 + gcol]);
  }
  __syncthreads();

  const int l  = tid & 63;
  const int wv = tid >> 6;           // K-split 0..7
  const int cl = l & 31;             // A-row / B-col
  const int q  = l >> 5;             // k-half

  // ---- B fragments -> registers (48 VGPR) ----
  bf16x8 ubf[8], wbf[4];
  {
    const u16* ub = Ut + cl * U_LD + wv * 128 + q * 8;
#pragma unroll
    for (int s = 0; s < 8; ++s) ubf[s] = *(const bf16x8*)(ub + s * 16);
    const u16* wb = Wt + cl * W_LD + wv * 64 + q * 8;
#pragma unroll
    for (int s = 0; s < 4; ++s) wbf[s] = *(const bf16x8*)(wb + s * 16);
  }
  __syncthreads();   // staging dead; zp live from here

  // gates (tid < 256): thread -> (row pb, unit pu); wave wv = gate-wave
  const int pb = tid >> 3;
  const int pu = tid & 7;
  const float bi  = bias[j0 + pu];
  const float bf_ = bias[1024 + j0 + pu];
  const float bg  = bias[2048 + j0 + pu];
  const float bo  = bias[3072 + j0 + pu];
  float cA = 0.f, cB = 0.f;
  int alive = 1;

  const uint64_t hbase = (uint64_t)ws + HB_OFF;
  const uint64_t fbase = (uint64_t)ws + FLG_OFF;
  const uint64_t xb64  = (uint64_t)xb;

  uint32x4 hA[8], xA[4], hB[8], xB[4];

  // ---- bootstrap: prefetch chain A step 0 into bufA (flags memset 0 => ready) ----
  {
    const uint64_t hbp = hbase + (uint64_t)cl * 16;   // ch0, parity0
#pragma unroll
    for (int s = 0; s < 8; ++s) hA[s] = load16_sc(hbp + (uint64_t)((wv * 16 + 2 * s + q) * 32) * 16);
    const uint64_t xap = xb64 + ((uint64_t)cl * 512 + (uint64_t)(wv * 64 + q * 8)) * 2;
#pragma unroll
    for (int s = 0; s < 4; ++s) xA[s] = load16_plain(xap + (uint64_t)s * 32);
  }

#define HMFMA(BUF, S) acc = __builtin_amdgcn_mfma_f32_32x32x16_bf16( \
    __builtin_bit_cast(bf16x8, BUF[S]), ubf[S], acc, 0, 0, 0)
#define XMFMA(BUF, S) acc = __builtin_amdgcn_mfma_f32_32x32x16_bf16( \
    __builtin_bit_cast(bf16x8, BUF[S]), wbf[S], acc, 0, 0, 0)

#define PHASE(CH, TT, HC, XC, HN, XN, CREG, OCH, OT) do {                        \
    WAITV(0); SBAR();  /* CUR resident (drains prev-phase prefetch) */           \
    f32x16 acc = {0.f,0.f,0.f,0.f,0.f,0.f,0.f,0.f,0.f,0.f,0.f,0.f,0.f,0.f,0.f,0.f}; \
    HMFMA(HC,0); HMFMA(HC,1); HMFMA(HC,2); HMFMA(HC,3);                          \
    HMFMA(HC,4); HMFMA(HC,5); HMFMA(HC,6); HMFMA(HC,7);                          \
    XMFMA(XC,0); XMFMA(XC,1); XMFMA(XC,2); XMFMA(XC,3);                          \
    _Pragma("unroll")                                                            \
    for (int r = 0; r < 16; ++r) {                                               \
      int rl = (r & 3) + 8 * (r >> 2) + 4 * q;                                   \
      zp[wv][rl][cl] = acc[r];                                                   \
    }                                                                            \
    __syncthreads();  /* b1: zp write -> read */                                 \
    if (tid < 256) {                                                             \
      float zi = bi, zf = bf_, zg = bg, zo = bo;                                 \
      _Pragma("unroll")                                                          \
      for (int k2 = 0; k2 < 8; ++k2) {                                           \
        float4 v = *(const float4*)&zp[k2][pb][pu * 4];                          \
        zi += v.x; zf += v.y; zg += v.z; zo += v.w;                              \
      }                                                                          \
      float ig = sigm(zi), fg = sigm(zf), og = sigm(zo);                         \
      float gg = fast_tanh(zg);                                                  \
      CREG = fg * CREG + ig * gg;                                                \
      float h = og * fast_tanh(CREG);                                            \
      unsigned hval = (unsigned)f2bf(h);                                         \
      unsigned other = __shfl_xor(hval, 1);                                      \
      unsigned pair32 = (l & 1) ? ((other & 0xffffu) | (hval << 16))             \
                                : ((hval & 0xffffu) | (other << 16));            \
      int base_ = l & ~7;                                                        \
      uint32x4 hv;                                                               \
      hv[0] = __shfl(pair32, base_);     hv[1] = __shfl(pair32, base_ + 2);      \
      hv[2] = __shfl(pair32, base_ + 4); hv[3] = __shfl(pair32, base_ + 6);      \
      if ((l & 7) == 0)                                                          \
        store16_sc(hbase + (uint64_t)(CH) * 131072 +                             \
                   (uint64_t)(((TT) + 1) & 1) * 65536 + (uint64_t)bid * 512 +    \
                   (uint64_t)(wv * 8 + (l >> 3)) * 16, hv);                      \
      if ((TT) == T_STEPS - 1) {                                                 \
        float* orow = out + (size_t)((CH) * 32 + pb) * 3072 + j0 + pu;           \
        orow[0] = h; orow[1024] = h; orow[2048] = CREG;                          \
      }                                                                          \
      WAITV(0);  /* ack own publish (prefetch long done) */                      \
      if (l == 0)                                                                \
        store4_sc(fbase + (uint64_t)(CH) * 8192 + (uint64_t)bid * 64 +           \
                  (uint64_t)wv * 16, (unsigned)((TT) + 1));                      \
    }                                                                            \
    if (alive) {  /* poll next chain's producers (bounded) */                    \
      const uint64_t fa = fbase + (uint64_t)(OCH) * 8192 +                       \
                          (uint64_t)(wv * 16 + (l >> 2)) * 64 +                  \
                          (uint64_t)(l & 3) * 16;                                \
      int spins = 0;                                                             \
      while (true) {                                                             \
        unsigned f = load4_sc(fa);                                               \
        WAITV(0);                                                                \
        if (__all(f >= (unsigned)(OT))) break;                                   \
        if (++spins > (1 << 22)) { alive = 0; break; }                           \
        __builtin_amdgcn_s_sleep(1);                                             \
      }                                                                          \
    }                                                                            \
    {  /* prefetch NXT: 8 h (sc1) + 4 x (plain) */                               \
      const uint64_t hbp = hbase + (uint64_t)(OCH) * 131072 +                    \
                           (uint64_t)((OT) & 1) * 65536 + (uint64_t)cl * 16;     \
      _Pragma("unroll")                                                          \
      for (int s = 0; s < 8; ++s)                                                \
        HN[s] = load16_sc(hbp + (uint64_t)((wv * 16 + 2 * s + q) * 32) * 16);    \
      const int otx = ((OT) < T_STEPS) ? (OT) : 0;                               \
      const uint64_t xap = xb64 + ((uint64_t)(otx * 64 + (OCH) * 32 + cl) * 512  \
                                   + (uint64_t)(wv * 64 + q * 8)) * 2;           \
      _Pragma("unroll")                                                          \
      for (int s = 0; s < 4; ++s) XN[s] = load16_plain(xap + (uint64_t)s * 32);  \
    }                                                                            \
    __syncthreads();  /* b2: zp read -> next write */                            \
  } while (0)

  for (int t = 0; t < T_STEPS; ++t) {
    PHASE(0, t, hA, xA, hB, xB, cA, 1, t);
    PHASE(1, t, hB, xB, hA, xA, cB, 0, t + 1);
  }
#undef PHASE
#undef HMFMA
#undef XMFMA
}

extern "C" void kernel_launch(void* const* d_in, const int* in_sizes, int n_in,
                              void* d_out, int out_size, void* d_ws, size_t ws_size,
                              hipStream_t stream) {
  const float* x = (const float*)d_in[0];
  const float* W = (const float*)d_in[1];
  const float* U = (const float*)d_in[2];
  const float* b = (const float*)d_in[3];
  float* out = (float*)d_out;

  if (ws_size < WS_NEED) return;  // loud failure: output stays poisoned

  u16* xb = (u16*)d_ws;
  // zero h (both chains, both parities) + flags — replayed every graph launch
  hipMemsetAsync((char*)d_ws + HB_OFF, 0, HB_BYTES + FLG_BYTES, stream);
  cvt_x<<<(T_STEPS * BATCH * DIN / 8 + 255) / 256, 256, 0, stream>>>(x, xb);
  lstm_kernel<<<NBLK, THREADS, 0, stream>>>(W, U, b, xb, (char*)d_ws, out);
}